// Round 3
// baseline (173.071 us; speedup 1.0000x reference)
//
#include <hip/hip_runtime.h>
#include <math.h>

#define HH   128
#define WW   160
#define HWN  (HH*WW)      // 20480
#define NCF  32           // feature channels
#define NCD  8            // deps channels
#define ND   32           // depths
#define NV   3            // views
#define LAMBF 1.5f

// ---------------------------------------------------------------------------
// Single fused kernel.
// block = (64 lanes = consecutive pixels) x (8 depth-groups); each thread
// handles 1 pixel x 4 depths x all 40 channels, gathering from the NATIVE
// channel-first layout so wave gathers are line-dense (lane = x).
// grid = HWN/64 = 320 blocks.
// ---------------------------------------------------------------------------
__global__ __launch_bounds__(512) void cost_volume_k(
    const float* __restrict__ feat,    // (V,32,H,W)
    const float* __restrict__ deps,    // (V,8,H,W)
    const float* __restrict__ proj,    // (V,4,4)
    const float* __restrict__ dvals,   // (D,H,W)
    const float* __restrict__ regw,    // 40
    float* __restrict__ out)
{
    __shared__ float pj[24];           // {rot9, tr3} x 2 views
    __shared__ float cl [ND][64];      // cost exchange
    __shared__ float dvl[ND][64];      // depth-value exchange

    const int lane = threadIdx.x;
    const int dg   = threadIdx.y;

    // ---- thread 0: rel projections via closed-form inverse (no pivoting,
    // constant indices -> stays in registers). ref bottom row is [0,0,0,1].
    if (lane == 0 && dg == 0) {
        float M00 = proj[0], M01 = proj[1], M02 = proj[2],  m0 = proj[3];
        float M10 = proj[4], M11 = proj[5], M12 = proj[6],  m1 = proj[7];
        float M20 = proj[8], M21 = proj[9], M22 = proj[10], m2 = proj[11];
        float c00 =  (M11*M22 - M12*M21);
        float c01 = -(M10*M22 - M12*M20);
        float c02 =  (M10*M21 - M11*M20);
        float det = M00*c00 + M01*c01 + M02*c02;
        float id  = 1.f / det;
        float i00 = c00*id, i01 = -(M01*M22 - M02*M21)*id, i02 =  (M01*M12 - M02*M11)*id;
        float i10 = c01*id, i11 =  (M00*M22 - M02*M20)*id, i12 = -(M00*M12 - M02*M10)*id;
        float i20 = c02*id, i21 = -(M00*M21 - M01*M20)*id, i22 =  (M00*M11 - M01*M10)*id;
        // t_inv = -Mi * m
        float t0 = -(i00*m0 + i01*m1 + i02*m2);
        float t1 = -(i10*m0 + i11*m1 + i12*m2);
        float t2 = -(i20*m0 + i21*m1 + i22*m2);
        #pragma unroll
        for (int v = 1; v < NV; v++) {
            const float* S = proj + v*16;
            float s00 = S[0], s01 = S[1], s02 = S[2],  st0 = S[3];
            float s10 = S[4], s11 = S[5], s12 = S[6],  st1 = S[7];
            float s20 = S[8], s21 = S[9], s22 = S[10], st2 = S[11];
            float* o = pj + (v-1)*12;
            o[0] = s00*i00 + s01*i10 + s02*i20;
            o[1] = s00*i01 + s01*i11 + s02*i21;
            o[2] = s00*i02 + s01*i12 + s02*i22;
            o[3] = s10*i00 + s11*i10 + s12*i20;
            o[4] = s10*i01 + s11*i11 + s12*i21;
            o[5] = s10*i02 + s11*i12 + s12*i22;
            o[6] = s20*i00 + s21*i10 + s22*i20;
            o[7] = s20*i01 + s21*i11 + s22*i21;
            o[8] = s20*i02 + s21*i12 + s22*i22;
            o[9]  = s00*t0 + s01*t1 + s02*t2 + st0;
            o[10] = s10*t0 + s11*t1 + s12*t2 + st1;
            o[11] = s20*t0 + s21*t1 + s22*t2 + st2;
        }
    }
    __syncthreads();

    const int pix = blockIdx.x * 64 + lane;
    const int y   = pix / WW;
    const int x   = pix - y * WW;
    const float fx = (float)x, fy = (float)y;

    // per-view ray (depth-independent)
    float RX[2], RY[2], RZ[2], T0[2], T1[2], T2[2];
    #pragma unroll
    for (int v = 0; v < 2; v++) {
        const float* q = pj + v*12;
        RX[v] = q[0]*fx + q[1]*fy + q[2];
        RY[v] = q[3]*fx + q[4]*fy + q[5];
        RZ[v] = q[6]*fx + q[7]*fy + q[8];
        T0[v] = q[9]; T1[v] = q[10]; T2[v] = q[11];
    }

    // per-(depth, view) bilinear setup
    float dv[4];
    int   l00[4][2], l10[4][2], l01[4][2], l11[4][2];
    float W00[4][2], W10[4][2], W01[4][2], W11[4][2];
    #pragma unroll
    for (int j = 0; j < 4; j++) {
        const int d = dg*4 + j;
        dv[j] = dvals[d*HWN + pix];
        #pragma unroll
        for (int v = 0; v < 2; v++) {
            float pz = RZ[v]*dv[j] + T2[v];
            float iz = 1.f / pz;
            float px = (RX[v]*dv[j] + T0[v]) * iz;
            float py = (RY[v]*dv[j] + T1[v]) * iz;
            float x0f = floorf(px), y0f = floorf(py);
            int x0 = (int)x0f, y0 = (int)y0f;
            float wx = px - x0f, wy = py - y0f;
            float omx = 1.f - wx, omy = 1.f - wy;
            bool vx0 = (x0 >= 0) & (x0 < WW);
            bool vx1 = (x0+1 >= 0) & (x0+1 < WW);
            bool vy0 = (y0 >= 0) & (y0 < HH);
            bool vy1 = (y0+1 >= 0) & (y0+1 < HH);
            W00[j][v] = (vx0 && vy0) ? omx*omy : 0.f;
            W10[j][v] = (vx1 && vy0) ? wx*omy  : 0.f;
            W01[j][v] = (vx0 && vy1) ? omx*wy  : 0.f;
            W11[j][v] = (vx1 && vy1) ? wx*wy   : 0.f;
            int xc0 = min(max(x0,     0), WW-1);
            int xc1 = min(max(x0 + 1, 0), WW-1);
            int yc0 = min(max(y0,     0), HH-1);
            int yc1 = min(max(y0 + 1, 0), HH-1);
            l00[j][v] = yc0*WW + xc0;
            l10[j][v] = yc0*WW + xc1;
            l01[j][v] = yc1*WW + xc0;
            l11[j][v] = yc1*WW + xc1;
        }
    }

    float cost[4] = {0.f, 0.f, 0.f, 0.f};

    auto do_ch = [&](const float* rb, const float* b1, const float* b2, float wc) {
        float r  = rb[pix];
        float r2 = r * r;
        float wca = wc * (1.f/3.f);
        float wcb = wc * (1.f/9.f);
        #pragma unroll
        for (int j = 0; j < 4; j++) {
            float s  = r;
            float sq = r2;
            #pragma unroll
            for (int v = 0; v < 2; v++) {
                const float* b = v ? b2 : b1;
                float f00 = b[l00[j][v]];
                float f10 = b[l10[j][v]];
                float f01 = b[l01[j][v]];
                float f11 = b[l11[j][v]];
                float wv = W00[j][v]*f00 + W10[j][v]*f10
                         + W01[j][v]*f01 + W11[j][v]*f11;
                s  += wv;
                sq += wv * wv;
            }
            cost[j] = fmaf(wca, sq, cost[j]);
            cost[j] = fmaf(-wcb, s*s, cost[j]);
        }
    };

    #pragma unroll 4
    for (int c = 0; c < NCF; c++)
        do_ch(feat + (size_t)c*HWN,
              feat + (size_t)(NCF   + c)*HWN,
              feat + (size_t)(2*NCF + c)*HWN,
              regw[c]);
    #pragma unroll 4
    for (int c = 0; c < NCD; c++)
        do_ch(deps + (size_t)c*HWN,
              deps + (size_t)(NCD   + c)*HWN,
              deps + (size_t)(2*NCD + c)*HWN,
              regw[NCF + c]);

    // ---- exchange cost/dv across depth-groups, then softmax + moments ----
    #pragma unroll
    for (int j = 0; j < 4; j++) {
        cl [dg*4 + j][lane] = cost[j];
        dvl[dg*4 + j][lane] = dv[j];
    }
    __syncthreads();

    float m = -1e30f;
    #pragma unroll
    for (int dd = 0; dd < ND; dd++) m = fmaxf(m, cl[dd][lane]);
    float sum = 0.f, pd = 0.f, pd2 = 0.f;
    #pragma unroll
    for (int dd = 0; dd < ND; dd++) {
        float e = __expf(cl[dd][lane] - m);
        float dvv = dvl[dd][lane];
        sum += e;
        pd  = fmaf(e, dvv, pd);
        pd2 = fmaf(e, dvv*dvv, pd2);
    }
    float isum  = 1.f / sum;
    float depth = pd * isum;
    float sv    = pd2 * isum - depth*depth;
    float ev    = LAMBF * sqrtf(fmaxf(sv, 0.f));

    #pragma unroll
    for (int j = 0; j < 4; j++)
        out[2*HWN + (dg*4 + j)*HWN + pix] = __expf(cost[j] - m) * isum;
    if (dg == 0) {
        out[pix]       = depth;
        out[HWN + pix] = ev;
    }
}

// ---------------------------------------------------------------------------
extern "C" void kernel_launch(void* const* d_in, const int* in_sizes, int n_in,
                              void* d_out, int out_size, void* d_ws, size_t ws_size,
                              hipStream_t stream) {
    const float* features = (const float*)d_in[0];   // (V,1,32,H,W)
    const float* deps     = (const float*)d_in[1];   // (V,1,8,H,W)
    const float* proj     = (const float*)d_in[2];   // (1,V,4,4)
    const float* dvals    = (const float*)d_in[3];   // (1,D,H,W)
    const float* regw     = (const float*)d_in[4];   // (1,40)

    dim3 blk(64, 8);
    cost_volume_k<<<HWN/64, blk, 0, stream>>>(features, deps, proj, dvals, regw,
                                              (float*)d_out);
}

// Round 4
// 151.237 us; speedup vs baseline: 1.1444x; 1.1444x over previous
//
#include <hip/hip_runtime.h>
#include <math.h>

#define HH   128
#define WW   160
#define HWN  (HH*WW)      // 20480
#define NCF  32           // feature channels
#define NCD  8            // deps channels
#define ND   32           // depths
#define NV   3            // views
#define LAMBF 1.5f

// ---------------------------------------------------------------------------
// Prep: transpose (V,CH,H,W) -> (V,HW,CH) channel-last for feat and deps.
// grid = (W/32, H, 6): z<3 feat views, z>=3 deps views.
// ---------------------------------------------------------------------------
__global__ __launch_bounds__(256) void prep_k(const float* __restrict__ feat,
                                              const float* __restrict__ deps,
                                              float* __restrict__ featT,
                                              float* __restrict__ depsT) {
    __shared__ float lds[NCF][33];
    const int z  = blockIdx.z;
    const int xb = blockIdx.x * 32;
    const int y  = blockIdx.y;
    const float* src;
    float*       dst;
    int CH;
    if (z < NV) {
        CH = NCF;
        src = feat + (size_t)(z*NCF)*HWN + y*WW + xb;
        dst = featT + (size_t)(z*HWN + y*WW + xb) * NCF;
    } else {
        CH = NCD;
        src = deps + (size_t)((z - NV)*NCD)*HWN + y*WW + xb;
        dst = depsT + (size_t)((z - NV)*HWN + y*WW + xb) * NCD;
    }
    for (int i = threadIdx.x; i < CH*32; i += 256) {
        int c = i >> 5, xl = i & 31;
        lds[c][xl] = src[c*HWN + xl];
    }
    __syncthreads();
    for (int i = threadIdx.x; i < CH*32; i += 256) {
        int c = i % CH, xl = i / CH;
        dst[i] = lds[c][xl];
    }
}

// ---------------------------------------------------------------------------
// Main: block = 256 threads = 4 waves = 32 consecutive pixels.
// Feat phase: wave lane = (pixel_in_wave<3b> , cg<3b low>) -> 8 pix x 8 cg.
// Deps phase: wave lane = (pixel_in_block<5b>, cg<1b low>) -> 32 pix x 2 cg,
//             wave w handles depths 8w..8w+7.
// ---------------------------------------------------------------------------
__global__ __launch_bounds__(256) void cost_volume_k(
    const float* __restrict__ featT,   // (V,HW,32)
    const float* __restrict__ depsT,   // (V,HW,8)
    const float* __restrict__ proj,    // (V,4,4)
    const float* __restrict__ dvals,   // (D,HW)
    const float* __restrict__ regw,    // 40
    float* __restrict__ out)
{
    __shared__ float pj[24];
    __shared__ float cl [ND][33];
    __shared__ float dvl[ND][33];

    const int t    = threadIdx.x;
    const int lane = t & 63;
    const int wid  = t >> 6;

    // ---- thread 0: relative projections (closed-form 3x3 inverse) ----
    if (t == 0) {
        float M00 = proj[0], M01 = proj[1], M02 = proj[2],  m0 = proj[3];
        float M10 = proj[4], M11 = proj[5], M12 = proj[6],  m1 = proj[7];
        float M20 = proj[8], M21 = proj[9], M22 = proj[10], m2 = proj[11];
        float c00 =  (M11*M22 - M12*M21);
        float c01 = -(M10*M22 - M12*M20);
        float c02 =  (M10*M21 - M11*M20);
        float det = M00*c00 + M01*c01 + M02*c02;
        float id  = 1.f / det;
        float i00 = c00*id, i01 = -(M01*M22 - M02*M21)*id, i02 =  (M01*M12 - M02*M11)*id;
        float i10 = c01*id, i11 =  (M00*M22 - M02*M20)*id, i12 = -(M00*M12 - M02*M10)*id;
        float i20 = c02*id, i21 = -(M00*M21 - M01*M20)*id, i22 =  (M00*M11 - M01*M10)*id;
        float t0 = -(i00*m0 + i01*m1 + i02*m2);
        float t1 = -(i10*m0 + i11*m1 + i12*m2);
        float t2 = -(i20*m0 + i21*m1 + i22*m2);
        #pragma unroll
        for (int v = 1; v < NV; v++) {
            const float* S = proj + v*16;
            float s00 = S[0], s01 = S[1], s02 = S[2],  st0 = S[3];
            float s10 = S[4], s11 = S[5], s12 = S[6],  st1 = S[7];
            float s20 = S[8], s21 = S[9], s22 = S[10], st2 = S[11];
            float* o = pj + (v-1)*12;
            o[0] = s00*i00 + s01*i10 + s02*i20;
            o[1] = s00*i01 + s01*i11 + s02*i21;
            o[2] = s00*i02 + s01*i12 + s02*i22;
            o[3] = s10*i00 + s11*i10 + s12*i20;
            o[4] = s10*i01 + s11*i11 + s12*i21;
            o[5] = s10*i02 + s11*i12 + s12*i22;
            o[6] = s20*i00 + s21*i10 + s22*i20;
            o[7] = s20*i01 + s21*i11 + s22*i21;
            o[8] = s20*i02 + s21*i12 + s22*i22;
            o[9]  = s00*t0 + s01*t1 + s02*t2 + st0;
            o[10] = s10*t0 + s11*t1 + s12*t2 + st1;
            o[11] = s20*t0 + s21*t1 + s22*t2 + st2;
        }
    }
    __syncthreads();

    // ================== FEAT PHASE: 8 pixels x 8 cg per wave ==================
    {
        const int cg  = lane & 7;
        const int pl  = wid*8 + (lane >> 3);          // 0..31 in block
        const int pixg = blockIdx.x * 32 + pl;
        const int y   = pixg / WW;
        const int x   = pixg - y * WW;
        const float fx = (float)x, fy = (float)y;

        float RX[2], RY[2], RZ[2], T0[2], T1[2], T2[2];
        #pragma unroll
        for (int v = 0; v < 2; v++) {
            const float* q = pj + v*12;
            RX[v] = q[0]*fx + q[1]*fy + q[2];
            RY[v] = q[3]*fx + q[4]*fy + q[5];
            RZ[v] = q[6]*fx + q[7]*fy + q[8];
            T0[v] = q[9]; T1[v] = q[10]; T2[v] = q[11];
        }

        float4 r4 = *(const float4*)(featT + (size_t)pixg*NCF + cg*4);
        float4 w4 = *(const float4*)(regw + cg*4);
        const float wca0 = w4.x*(1.f/3.f), wca1 = w4.y*(1.f/3.f),
                    wca2 = w4.z*(1.f/3.f), wca3 = w4.w*(1.f/3.f);
        const float wcb0 = w4.x*(1.f/9.f), wcb1 = w4.y*(1.f/9.f),
                    wcb2 = w4.z*(1.f/9.f), wcb3 = w4.w*(1.f/9.f);
        const float rx0 = r4.x, rx1 = r4.y, rx2 = r4.z, rx3 = r4.w;

        #pragma unroll 2
        for (int d = 0; d < ND; d++) {
            float dvv = dvals[d*HWN + pixg];
            if (cg == 0) dvl[d][pl] = dvv;

            float s0 = rx0, s1 = rx1, s2 = rx2, s3 = rx3;
            float q0 = rx0*rx0, q1 = rx1*rx1, q2 = rx2*rx2, q3 = rx3*rx3;

            #pragma unroll
            for (int v = 0; v < 2; v++) {
                float pz = RZ[v]*dvv + T2[v];
                float iz = 1.f / pz;
                float px = (RX[v]*dvv + T0[v]) * iz;
                float py = (RY[v]*dvv + T1[v]) * iz;
                float x0f = floorf(px), y0f = floorf(py);
                int x0 = (int)x0f, y0 = (int)y0f;
                float wx = px - x0f, wy = py - y0f;
                float omx = 1.f - wx, omy = 1.f - wy;
                bool vx0 = (x0 >= 0) & (x0 < WW);
                bool vx1 = (x0+1 >= 0) & (x0+1 < WW);
                bool vy0 = (y0 >= 0) & (y0 < HH);
                bool vy1 = (y0+1 >= 0) & (y0+1 < HH);
                float W00 = (vx0 && vy0) ? omx*omy : 0.f;
                float W10 = (vx1 && vy0) ? wx*omy  : 0.f;
                float W01 = (vx0 && vy1) ? omx*wy  : 0.f;
                float W11 = (vx1 && vy1) ? wx*wy   : 0.f;
                int xc0 = min(max(x0,   0), WW-1);
                int xc1 = min(max(x0+1, 0), WW-1);
                int yc0 = min(max(y0,   0), HH-1);
                int yc1 = min(max(y0+1, 0), HH-1);
                const float* b = featT + ((size_t)(v+1)*HWN)*NCF + cg*4;
                float4 f00 = *(const float4*)(b + (size_t)(yc0*WW + xc0)*NCF);
                float4 f10 = *(const float4*)(b + (size_t)(yc0*WW + xc1)*NCF);
                float4 f01 = *(const float4*)(b + (size_t)(yc1*WW + xc0)*NCF);
                float4 f11 = *(const float4*)(b + (size_t)(yc1*WW + xc1)*NCF);
                float wv0 = W00*f00.x + W10*f10.x + W01*f01.x + W11*f11.x;
                float wv1 = W00*f00.y + W10*f10.y + W01*f01.y + W11*f11.y;
                float wv2 = W00*f00.z + W10*f10.z + W01*f01.z + W11*f11.z;
                float wv3 = W00*f00.w + W10*f10.w + W01*f01.w + W11*f11.w;
                s0 += wv0; q0 = fmaf(wv0, wv0, q0);
                s1 += wv1; q1 = fmaf(wv1, wv1, q1);
                s2 += wv2; q2 = fmaf(wv2, wv2, q2);
                s3 += wv3; q3 = fmaf(wv3, wv3, q3);
            }
            float part = wca0*q0 - wcb0*s0*s0;
            part = fmaf(wca1, q1, part); part = fmaf(-wcb1, s1*s1, part);
            part = fmaf(wca2, q2, part); part = fmaf(-wcb2, s2*s2, part);
            part = fmaf(wca3, q3, part); part = fmaf(-wcb3, s3*s3, part);
            part += __shfl_xor(part, 1);
            part += __shfl_xor(part, 2);
            part += __shfl_xor(part, 4);
            if (cg == 0) cl[d][pl] = part;
        }
    }
    __syncthreads();

    // ================== DEPS PHASE: 32 pixels x 2 cg per wave =================
    {
        const int cg  = lane & 1;
        const int pl  = lane >> 1;                    // 0..31
        const int pixg = blockIdx.x * 32 + pl;
        const int y   = pixg / WW;
        const int x   = pixg - y * WW;
        const float fx = (float)x, fy = (float)y;

        float RX[2], RY[2], RZ[2], T0[2], T1[2], T2[2];
        #pragma unroll
        for (int v = 0; v < 2; v++) {
            const float* q = pj + v*12;
            RX[v] = q[0]*fx + q[1]*fy + q[2];
            RY[v] = q[3]*fx + q[4]*fy + q[5];
            RZ[v] = q[6]*fx + q[7]*fy + q[8];
            T0[v] = q[9]; T1[v] = q[10]; T2[v] = q[11];
        }

        float4 r4 = *(const float4*)(depsT + (size_t)pixg*NCD + cg*4);
        float4 w4 = *(const float4*)(regw + NCF + cg*4);
        const float wca0 = w4.x*(1.f/3.f), wca1 = w4.y*(1.f/3.f),
                    wca2 = w4.z*(1.f/3.f), wca3 = w4.w*(1.f/3.f);
        const float wcb0 = w4.x*(1.f/9.f), wcb1 = w4.y*(1.f/9.f),
                    wcb2 = w4.z*(1.f/9.f), wcb3 = w4.w*(1.f/9.f);
        const float rx0 = r4.x, rx1 = r4.y, rx2 = r4.z, rx3 = r4.w;

        #pragma unroll 2
        for (int j8 = 0; j8 < 8; j8++) {
            const int d = wid*8 + j8;
            float dvv = dvl[d][pl];

            float s0 = rx0, s1 = rx1, s2 = rx2, s3 = rx3;
            float q0 = rx0*rx0, q1 = rx1*rx1, q2 = rx2*rx2, q3 = rx3*rx3;

            #pragma unroll
            for (int v = 0; v < 2; v++) {
                float pz = RZ[v]*dvv + T2[v];
                float iz = 1.f / pz;
                float px = (RX[v]*dvv + T0[v]) * iz;
                float py = (RY[v]*dvv + T1[v]) * iz;
                float x0f = floorf(px), y0f = floorf(py);
                int x0 = (int)x0f, y0 = (int)y0f;
                float wx = px - x0f, wy = py - y0f;
                float omx = 1.f - wx, omy = 1.f - wy;
                bool vx0 = (x0 >= 0) & (x0 < WW);
                bool vx1 = (x0+1 >= 0) & (x0+1 < WW);
                bool vy0 = (y0 >= 0) & (y0 < HH);
                bool vy1 = (y0+1 >= 0) & (y0+1 < HH);
                float W00 = (vx0 && vy0) ? omx*omy : 0.f;
                float W10 = (vx1 && vy0) ? wx*omy  : 0.f;
                float W01 = (vx0 && vy1) ? omx*wy  : 0.f;
                float W11 = (vx1 && vy1) ? wx*wy   : 0.f;
                int xc0 = min(max(x0,   0), WW-1);
                int xc1 = min(max(x0+1, 0), WW-1);
                int yc0 = min(max(y0,   0), HH-1);
                int yc1 = min(max(y0+1, 0), HH-1);
                const float* b = depsT + ((size_t)(v+1)*HWN)*NCD + cg*4;
                float4 f00 = *(const float4*)(b + (size_t)(yc0*WW + xc0)*NCD);
                float4 f10 = *(const float4*)(b + (size_t)(yc0*WW + xc1)*NCD);
                float4 f01 = *(const float4*)(b + (size_t)(yc1*WW + xc0)*NCD);
                float4 f11 = *(const float4*)(b + (size_t)(yc1*WW + xc1)*NCD);
                float wv0 = W00*f00.x + W10*f10.x + W01*f01.x + W11*f11.x;
                float wv1 = W00*f00.y + W10*f10.y + W01*f01.y + W11*f11.y;
                float wv2 = W00*f00.z + W10*f10.z + W01*f01.z + W11*f11.z;
                float wv3 = W00*f00.w + W10*f10.w + W01*f01.w + W11*f11.w;
                s0 += wv0; q0 = fmaf(wv0, wv0, q0);
                s1 += wv1; q1 = fmaf(wv1, wv1, q1);
                s2 += wv2; q2 = fmaf(wv2, wv2, q2);
                s3 += wv3; q3 = fmaf(wv3, wv3, q3);
            }
            float part = wca0*q0 - wcb0*s0*s0;
            part = fmaf(wca1, q1, part); part = fmaf(-wcb1, s1*s1, part);
            part = fmaf(wca2, q2, part); part = fmaf(-wcb2, s2*s2, part);
            part = fmaf(wca3, q3, part); part = fmaf(-wcb3, s3*s3, part);
            part += __shfl_xor(part, 1);
            if (cg == 0) cl[d][pl] += part;   // disjoint d-ranges per wave
        }
    }
    __syncthreads();

    // ================== SOFTMAX + MOMENTS ==================
    {
        const int pl   = t & 31;
        const int pixg = blockIdx.x * 32 + pl;

        float m = -1e30f;
        #pragma unroll
        for (int d = 0; d < ND; d++) m = fmaxf(m, cl[d][pl]);
        float sum = 0.f, pd = 0.f, pd2 = 0.f;
        #pragma unroll
        for (int d = 0; d < ND; d++) {
            float e   = __expf(cl[d][pl] - m);
            float dvv = dvl[d][pl];
            sum += e;
            pd  = fmaf(e, dvv, pd);
            pd2 = fmaf(e, dvv*dvv, pd2);
        }
        float isum  = 1.f / sum;
        float depth = pd * isum;
        float sv    = pd2 * isum - depth*depth;
        float ev    = LAMBF * sqrtf(fmaxf(sv, 0.f));

        const int db = (t >> 5) * 4;
        #pragma unroll
        for (int j = 0; j < 4; j++) {
            int d = db + j;
            out[2*HWN + d*HWN + pixg] = __expf(cl[d][pl] - m) * isum;
        }
        if (t < 32) {
            out[pixg]       = depth;
            out[HWN + pixg] = ev;
        }
    }
}

// ---------------------------------------------------------------------------
extern "C" void kernel_launch(void* const* d_in, const int* in_sizes, int n_in,
                              void* d_out, int out_size, void* d_ws, size_t ws_size,
                              hipStream_t stream) {
    const float* features = (const float*)d_in[0];   // (V,1,32,H,W)
    const float* deps     = (const float*)d_in[1];   // (V,1,8,H,W)
    const float* proj     = (const float*)d_in[2];   // (1,V,4,4)
    const float* dvals    = (const float*)d_in[3];   // (1,D,H,W)
    const float* regw     = (const float*)d_in[4];   // (1,40)

    float* ws    = (float*)d_ws;
    float* featT = ws + 64;
    float* depsT = featT + (size_t)NV*HWN*NCF;

    dim3 tg(WW/32, HH, 2*NV);
    prep_k<<<tg, 256, 0, stream>>>(features, deps, featT, depsT);

    cost_volume_k<<<HWN/32, 256, 0, stream>>>(featT, depsT, proj, dvals, regw,
                                              (float*)d_out);
}

// Round 5
// 106.336 us; speedup vs baseline: 1.6276x; 1.4223x over previous
//
#include <hip/hip_runtime.h>
#include <math.h>

#define HH   128
#define WW   160
#define HWN  (HH*WW)      // 20480
#define NCF  32           // feature channels
#define NCD  8            // deps channels
#define ND   32           // depths
#define NV   3            // views
#define LAMBF 1.5f

// ---------------------------------------------------------------------------
// Prep: transpose (V,CH,H,W) -> (V,HW,CH) channel-last for feat and deps,
// and block(0,0,0)/thread0 computes proj_v @ inv(proj_ref) -> projw[24].
// grid = (W/32, H, 6): z<3 feat views, z>=3 deps views.
// ---------------------------------------------------------------------------
__global__ __launch_bounds__(256) void prep_k(const float* __restrict__ feat,
                                              const float* __restrict__ deps,
                                              const float* __restrict__ proj,
                                              float* __restrict__ featT,
                                              float* __restrict__ depsT,
                                              float* __restrict__ projw) {
    if (blockIdx.x == 0 && blockIdx.y == 0 && blockIdx.z == 0 && threadIdx.x == 0) {
        // closed-form 3x3 inverse (ref proj bottom row = [0,0,0,1])
        float M00 = proj[0], M01 = proj[1], M02 = proj[2],  m0 = proj[3];
        float M10 = proj[4], M11 = proj[5], M12 = proj[6],  m1 = proj[7];
        float M20 = proj[8], M21 = proj[9], M22 = proj[10], m2 = proj[11];
        float c00 =  (M11*M22 - M12*M21);
        float c01 = -(M10*M22 - M12*M20);
        float c02 =  (M10*M21 - M11*M20);
        float det = M00*c00 + M01*c01 + M02*c02;
        float id  = 1.f / det;
        float i00 = c00*id, i01 = -(M01*M22 - M02*M21)*id, i02 =  (M01*M12 - M02*M11)*id;
        float i10 = c01*id, i11 =  (M00*M22 - M02*M20)*id, i12 = -(M00*M12 - M02*M10)*id;
        float i20 = c02*id, i21 = -(M00*M21 - M01*M20)*id, i22 =  (M00*M11 - M01*M10)*id;
        float t0 = -(i00*m0 + i01*m1 + i02*m2);
        float t1 = -(i10*m0 + i11*m1 + i12*m2);
        float t2 = -(i20*m0 + i21*m1 + i22*m2);
        #pragma unroll
        for (int v = 1; v < NV; v++) {
            const float* S = proj + v*16;
            float s00 = S[0], s01 = S[1], s02 = S[2],  st0 = S[3];
            float s10 = S[4], s11 = S[5], s12 = S[6],  st1 = S[7];
            float s20 = S[8], s21 = S[9], s22 = S[10], st2 = S[11];
            float* o = projw + (v-1)*12;
            o[0] = s00*i00 + s01*i10 + s02*i20;
            o[1] = s00*i01 + s01*i11 + s02*i21;
            o[2] = s00*i02 + s01*i12 + s02*i22;
            o[3] = s10*i00 + s11*i10 + s12*i20;
            o[4] = s10*i01 + s11*i11 + s12*i21;
            o[5] = s10*i02 + s11*i12 + s12*i22;
            o[6] = s20*i00 + s21*i10 + s22*i20;
            o[7] = s20*i01 + s21*i11 + s22*i21;
            o[8] = s20*i02 + s21*i12 + s22*i22;
            o[9]  = s00*t0 + s01*t1 + s02*t2 + st0;
            o[10] = s10*t0 + s11*t1 + s12*t2 + st1;
            o[11] = s20*t0 + s21*t1 + s22*t2 + st2;
        }
    }

    __shared__ float lds[NCF][33];
    const int z  = blockIdx.z;
    const int xb = blockIdx.x * 32;
    const int y  = blockIdx.y;
    const float* src;
    float*       dst;
    int CH;
    if (z < NV) {
        CH = NCF;
        src = feat + (size_t)(z*NCF)*HWN + y*WW + xb;
        dst = featT + (size_t)(z*HWN + y*WW + xb) * NCF;
    } else {
        CH = NCD;
        src = deps + (size_t)((z - NV)*NCD)*HWN + y*WW + xb;
        dst = depsT + (size_t)((z - NV)*HWN + y*WW + xb) * NCD;
    }
    for (int i = threadIdx.x; i < CH*32; i += 256) {
        int c = i >> 5, xl = i & 31;
        lds[c][xl] = src[c*HWN + xl];
    }
    __syncthreads();
    for (int i = threadIdx.x; i < CH*32; i += 256) {
        int c = i % CH, xl = i / CH;
        dst[i] = lds[c][xl];
    }
}

// ---------------------------------------------------------------------------
// Main: block = 256 threads = 4 waves = 8 pixels x 32 depths.
// Wave w handles depths 8w..8w+7.
// Feat phase: lane = (pl<3b high>, cg<3b low>) -> 8 pix x 8 float4-groups.
// Deps phase: lane = (pl<3b high>, dsub<2b>, cg<1b low>) -> 8 pix x 4 d x 2 cg.
// grid = HWN/8 = 2560 blocks.
// ---------------------------------------------------------------------------
__global__ __launch_bounds__(256) void cost_volume_k(
    const float* __restrict__ featT,   // (V,HW,32)
    const float* __restrict__ depsT,   // (V,HW,8)
    const float* __restrict__ dvals,   // (D,HW)
    const float* __restrict__ regw,    // 40
    const float* __restrict__ pws,     // 24 (uniform -> scalar loads)
    float* __restrict__ out)
{
    __shared__ float cl [ND][9];
    __shared__ float dvl[ND][9];
    __shared__ float smax[8], sisum[8];

    const int t    = threadIdx.x;
    const int lane = t & 63;
    const int wid  = t >> 6;
    const int cg   = lane & 7;
    const int pl   = lane >> 3;
    const int pixg = blockIdx.x * 8 + pl;
    const int y    = pixg / WW;
    const int x    = pixg - y * WW;
    const float fx = (float)x, fy = (float)y;
    const int dbase = wid * 8;

    // per-view ray (depth-independent); pws is uniform -> s_loads
    float RX[2], RY[2], RZ[2], T0[2], T1[2], T2[2];
    #pragma unroll
    for (int v = 0; v < 2; v++) {
        const float* q = pws + v*12;
        RX[v] = q[0]*fx + q[1]*fy + q[2];
        RY[v] = q[3]*fx + q[4]*fy + q[5];
        RZ[v] = q[6]*fx + q[7]*fy + q[8];
        T0[v] = q[9]; T1[v] = q[10]; T2[v] = q[11];
    }

    // ================== FEAT PHASE ==================
    {
        float4 r4 = *(const float4*)(featT + (size_t)pixg*NCF + cg*4);
        float4 w4 = *(const float4*)(regw + cg*4);
        const float wca0 = w4.x*(1.f/3.f), wca1 = w4.y*(1.f/3.f),
                    wca2 = w4.z*(1.f/3.f), wca3 = w4.w*(1.f/3.f);
        const float wcb0 = w4.x*(1.f/9.f), wcb1 = w4.y*(1.f/9.f),
                    wcb2 = w4.z*(1.f/9.f), wcb3 = w4.w*(1.f/9.f);
        const float rx0 = r4.x, rx1 = r4.y, rx2 = r4.z, rx3 = r4.w;
        const float* b1 = featT + (size_t)1*HWN*NCF;
        const float* b2 = featT + (size_t)2*HWN*NCF;
        const int cg4 = cg*4;

        #pragma unroll 2
        for (int jj = 0; jj < 8; jj++) {
            const int d = dbase + jj;
            float dvv = dvals[d*HWN + pixg];
            if (cg == 0) dvl[d][pl] = dvv;

            float s0 = rx0, s1 = rx1, s2 = rx2, s3 = rx3;
            float q0 = rx0*rx0, q1 = rx1*rx1, q2 = rx2*rx2, q3 = rx3*rx3;

            #pragma unroll
            for (int v = 0; v < 2; v++) {
                float pz = RZ[v]*dvv + T2[v];
                float iz = __builtin_amdgcn_rcpf(pz);
                float px = (RX[v]*dvv + T0[v]) * iz;
                float py = (RY[v]*dvv + T1[v]) * iz;
                float x0f = floorf(px), y0f = floorf(py);
                int x0 = (int)x0f, y0 = (int)y0f;
                float wx = px - x0f, wy = py - y0f;
                float omx = 1.f - wx, omy = 1.f - wy;
                bool vx0 = (x0 >= 0) & (x0 < WW);
                bool vx1 = (x0+1 >= 0) & (x0+1 < WW);
                bool vy0 = (y0 >= 0) & (y0 < HH);
                bool vy1 = (y0+1 >= 0) & (y0+1 < HH);
                float W00 = (vx0 && vy0) ? omx*omy : 0.f;
                float W10 = (vx1 && vy0) ? wx*omy  : 0.f;
                float W01 = (vx0 && vy1) ? omx*wy  : 0.f;
                float W11 = (vx1 && vy1) ? wx*wy   : 0.f;
                int xc0 = min(max(x0,   0), WW-1);
                int xc1 = min(max(x0+1, 0), WW-1);
                int yc0 = min(max(y0,   0), HH-1);
                int yc1 = min(max(y0+1, 0), HH-1);
                const float* b = v ? b2 : b1;
                int o00 = (yc0*WW + xc0)*NCF + cg4;
                int o10 = (yc0*WW + xc1)*NCF + cg4;
                int o01 = (yc1*WW + xc0)*NCF + cg4;
                int o11 = (yc1*WW + xc1)*NCF + cg4;
                float4 f00 = *(const float4*)(b + o00);
                float4 f10 = *(const float4*)(b + o10);
                float4 f01 = *(const float4*)(b + o01);
                float4 f11 = *(const float4*)(b + o11);
                float wv0 = W00*f00.x + W10*f10.x + W01*f01.x + W11*f11.x;
                float wv1 = W00*f00.y + W10*f10.y + W01*f01.y + W11*f11.y;
                float wv2 = W00*f00.z + W10*f10.z + W01*f01.z + W11*f11.z;
                float wv3 = W00*f00.w + W10*f10.w + W01*f01.w + W11*f11.w;
                s0 += wv0; q0 = fmaf(wv0, wv0, q0);
                s1 += wv1; q1 = fmaf(wv1, wv1, q1);
                s2 += wv2; q2 = fmaf(wv2, wv2, q2);
                s3 += wv3; q3 = fmaf(wv3, wv3, q3);
            }
            float part = wca0*q0 - wcb0*s0*s0;
            part = fmaf(wca1, q1, part); part = fmaf(-wcb1, s1*s1, part);
            part = fmaf(wca2, q2, part); part = fmaf(-wcb2, s2*s2, part);
            part = fmaf(wca3, q3, part); part = fmaf(-wcb3, s3*s3, part);
            part += __shfl_xor(part, 1);
            part += __shfl_xor(part, 2);
            part += __shfl_xor(part, 4);
            if (cg == 0) cl[d][pl] = part;
        }
    }
    __syncthreads();

    // ================== DEPS PHASE ==================
    {
        const int cgd  = lane & 1;       // float4 group in 8 channels
        const int dsub = (lane >> 1) & 3;
        float4 r4 = *(const float4*)(depsT + (size_t)pixg*NCD + cgd*4);
        float4 w4 = *(const float4*)(regw + NCF + cgd*4);
        const float wca0 = w4.x*(1.f/3.f), wca1 = w4.y*(1.f/3.f),
                    wca2 = w4.z*(1.f/3.f), wca3 = w4.w*(1.f/3.f);
        const float wcb0 = w4.x*(1.f/9.f), wcb1 = w4.y*(1.f/9.f),
                    wcb2 = w4.z*(1.f/9.f), wcb3 = w4.w*(1.f/9.f);
        const float rx0 = r4.x, rx1 = r4.y, rx2 = r4.z, rx3 = r4.w;
        const float* b1 = depsT + (size_t)1*HWN*NCD;
        const float* b2 = depsT + (size_t)2*HWN*NCD;
        const int cg4 = cgd*4;

        #pragma unroll
        for (int i = 0; i < 2; i++) {
            const int d = dbase + dsub + 4*i;
            float dvv = dvl[d][pl];

            float s0 = rx0, s1 = rx1, s2 = rx2, s3 = rx3;
            float q0 = rx0*rx0, q1 = rx1*rx1, q2 = rx2*rx2, q3 = rx3*rx3;

            #pragma unroll
            for (int v = 0; v < 2; v++) {
                float pz = RZ[v]*dvv + T2[v];
                float iz = __builtin_amdgcn_rcpf(pz);
                float px = (RX[v]*dvv + T0[v]) * iz;
                float py = (RY[v]*dvv + T1[v]) * iz;
                float x0f = floorf(px), y0f = floorf(py);
                int x0 = (int)x0f, y0 = (int)y0f;
                float wx = px - x0f, wy = py - y0f;
                float omx = 1.f - wx, omy = 1.f - wy;
                bool vx0 = (x0 >= 0) & (x0 < WW);
                bool vx1 = (x0+1 >= 0) & (x0+1 < WW);
                bool vy0 = (y0 >= 0) & (y0 < HH);
                bool vy1 = (y0+1 >= 0) & (y0+1 < HH);
                float W00 = (vx0 && vy0) ? omx*omy : 0.f;
                float W10 = (vx1 && vy0) ? wx*omy  : 0.f;
                float W01 = (vx0 && vy1) ? omx*wy  : 0.f;
                float W11 = (vx1 && vy1) ? wx*wy   : 0.f;
                int xc0 = min(max(x0,   0), WW-1);
                int xc1 = min(max(x0+1, 0), WW-1);
                int yc0 = min(max(y0,   0), HH-1);
                int yc1 = min(max(y0+1, 0), HH-1);
                const float* b = v ? b2 : b1;
                int o00 = (yc0*WW + xc0)*NCD + cg4;
                int o10 = (yc0*WW + xc1)*NCD + cg4;
                int o01 = (yc1*WW + xc0)*NCD + cg4;
                int o11 = (yc1*WW + xc1)*NCD + cg4;
                float4 f00 = *(const float4*)(b + o00);
                float4 f10 = *(const float4*)(b + o10);
                float4 f01 = *(const float4*)(b + o01);
                float4 f11 = *(const float4*)(b + o11);
                float wv0 = W00*f00.x + W10*f10.x + W01*f01.x + W11*f11.x;
                float wv1 = W00*f00.y + W10*f10.y + W01*f01.y + W11*f11.y;
                float wv2 = W00*f00.z + W10*f10.z + W01*f01.z + W11*f11.z;
                float wv3 = W00*f00.w + W10*f10.w + W01*f01.w + W11*f11.w;
                s0 += wv0; q0 = fmaf(wv0, wv0, q0);
                s1 += wv1; q1 = fmaf(wv1, wv1, q1);
                s2 += wv2; q2 = fmaf(wv2, wv2, q2);
                s3 += wv3; q3 = fmaf(wv3, wv3, q3);
            }
            float part = wca0*q0 - wcb0*s0*s0;
            part = fmaf(wca1, q1, part); part = fmaf(-wcb1, s1*s1, part);
            part = fmaf(wca2, q2, part); part = fmaf(-wcb2, s2*s2, part);
            part = fmaf(wca3, q3, part); part = fmaf(-wcb3, s3*s3, part);
            part += __shfl_xor(part, 1);
            if (cgd == 0) cl[d][pl] += part;
        }
    }
    __syncthreads();

    // ================== SOFTMAX + MOMENTS ==================
    if (t < 8) {
        const int plx  = t;
        const int pixo = blockIdx.x * 8 + plx;
        float m = -1e30f;
        #pragma unroll
        for (int d = 0; d < ND; d++) m = fmaxf(m, cl[d][plx]);
        float sum = 0.f, pd = 0.f, pd2 = 0.f;
        #pragma unroll
        for (int d = 0; d < ND; d++) {
            float e   = __expf(cl[d][plx] - m);
            float dvv = dvl[d][plx];
            sum += e;
            pd  = fmaf(e, dvv, pd);
            pd2 = fmaf(e, dvv*dvv, pd2);
        }
        float isum  = 1.f / sum;
        float depth = pd * isum;
        float sv    = pd2 * isum - depth*depth;
        float ev    = LAMBF * sqrtf(fmaxf(sv, 0.f));
        smax[plx]  = m;
        sisum[plx] = isum;
        out[pixo]       = depth;
        out[HWN + pixo] = ev;
    }
    __syncthreads();
    {
        const int plx  = t & 7;
        const int dd   = t >> 3;
        const int pixo = blockIdx.x * 8 + plx;
        out[2*HWN + dd*HWN + pixo] = __expf(cl[dd][plx] - smax[plx]) * sisum[plx];
    }
}

// ---------------------------------------------------------------------------
extern "C" void kernel_launch(void* const* d_in, const int* in_sizes, int n_in,
                              void* d_out, int out_size, void* d_ws, size_t ws_size,
                              hipStream_t stream) {
    const float* features = (const float*)d_in[0];   // (V,1,32,H,W)
    const float* deps     = (const float*)d_in[1];   // (V,1,8,H,W)
    const float* proj     = (const float*)d_in[2];   // (1,V,4,4)
    const float* dvals    = (const float*)d_in[3];   // (1,D,H,W)
    const float* regw     = (const float*)d_in[4];   // (1,40)

    float* ws    = (float*)d_ws;
    float* projw = ws;                         // 24 floats (64 reserved)
    float* featT = ws + 64;                    // 3*HW*32
    float* depsT = featT + (size_t)NV*HWN*NCF; // 3*HW*8

    dim3 tg(WW/32, HH, 2*NV);
    prep_k<<<tg, 256, 0, stream>>>(features, deps, proj, featT, depsT, projw);

    cost_volume_k<<<HWN/8, 256, 0, stream>>>(featT, depsT, dvals, regw, projw,
                                             (float*)d_out);
}

// Round 6
// 103.906 us; speedup vs baseline: 1.6656x; 1.0234x over previous
//
#include <hip/hip_runtime.h>
#include <math.h>

#define HH   128
#define WW   160
#define HWN  (HH*WW)      // 20480
#define NCF  32           // feature channels
#define NCD  8            // deps channels
#define ND   32           // depths
#define NV   3            // views
#define LAMBF 1.5f

// ---------------------------------------------------------------------------
// Prep: transpose (V,CH,H,W) -> (V,HW,CH) channel-last, float4 both sides.
// block(0,0,0)/thread0 also computes proj_v @ inv(proj_ref) -> projw[24].
// grid = (W/32, H, 6): z<3 feat views, z>=3 deps views.
// ---------------------------------------------------------------------------
template <int CH>
__device__ void transpose_tile(const float* __restrict__ src, float* __restrict__ dst,
                               float (*lds)[33], int tid) {
    // load CH rows x 32 px, float4 (rows are 16B-aligned: HWN, y*WW+xb all mult of 4)
    for (int i = tid; i < CH*8; i += 256) {
        int c = i >> 3, xg = (i & 7) << 2;
        *(float4*)&lds[c][xg] = *(const float4*)(src + c*HWN + xg);
    }
    __syncthreads();
    // store 32 px x CH, float4 along channels
    for (int i = tid; i < 32*(CH/4); i += 256) {
        int xl = i / (CH/4), c4 = (i % (CH/4)) * 4;
        float4 t = make_float4(lds[c4][xl], lds[c4+1][xl], lds[c4+2][xl], lds[c4+3][xl]);
        *(float4*)(dst + xl*CH + c4) = t;
    }
}

__global__ __launch_bounds__(256) void prep_k(const float* __restrict__ feat,
                                              const float* __restrict__ deps,
                                              const float* __restrict__ proj,
                                              float* __restrict__ featT,
                                              float* __restrict__ depsT,
                                              float* __restrict__ projw) {
    if (blockIdx.x == 0 && blockIdx.y == 0 && blockIdx.z == 0 && threadIdx.x == 0) {
        // closed-form 3x3 inverse (ref proj bottom row = [0,0,0,1])
        float M00 = proj[0], M01 = proj[1], M02 = proj[2],  m0 = proj[3];
        float M10 = proj[4], M11 = proj[5], M12 = proj[6],  m1 = proj[7];
        float M20 = proj[8], M21 = proj[9], M22 = proj[10], m2 = proj[11];
        float c00 =  (M11*M22 - M12*M21);
        float c01 = -(M10*M22 - M12*M20);
        float c02 =  (M10*M21 - M11*M20);
        float det = M00*c00 + M01*c01 + M02*c02;
        float id  = 1.f / det;
        float i00 = c00*id, i01 = -(M01*M22 - M02*M21)*id, i02 =  (M01*M12 - M02*M11)*id;
        float i10 = c01*id, i11 =  (M00*M22 - M02*M20)*id, i12 = -(M00*M12 - M02*M10)*id;
        float i20 = c02*id, i21 = -(M00*M21 - M01*M20)*id, i22 =  (M00*M11 - M01*M10)*id;
        float t0 = -(i00*m0 + i01*m1 + i02*m2);
        float t1 = -(i10*m0 + i11*m1 + i12*m2);
        float t2 = -(i20*m0 + i21*m1 + i22*m2);
        #pragma unroll
        for (int v = 1; v < NV; v++) {
            const float* S = proj + v*16;
            float s00 = S[0], s01 = S[1], s02 = S[2],  st0 = S[3];
            float s10 = S[4], s11 = S[5], s12 = S[6],  st1 = S[7];
            float s20 = S[8], s21 = S[9], s22 = S[10], st2 = S[11];
            float* o = projw + (v-1)*12;
            o[0] = s00*i00 + s01*i10 + s02*i20;
            o[1] = s00*i01 + s01*i11 + s02*i21;
            o[2] = s00*i02 + s01*i12 + s02*i22;
            o[3] = s10*i00 + s11*i10 + s12*i20;
            o[4] = s10*i01 + s11*i11 + s12*i21;
            o[5] = s10*i02 + s11*i12 + s12*i22;
            o[6] = s20*i00 + s21*i10 + s22*i20;
            o[7] = s20*i01 + s21*i11 + s22*i21;
            o[8] = s20*i02 + s21*i12 + s22*i22;
            o[9]  = s00*t0 + s01*t1 + s02*t2 + st0;
            o[10] = s10*t0 + s11*t1 + s12*t2 + st1;
            o[11] = s20*t0 + s21*t1 + s22*t2 + st2;
        }
    }

    __shared__ float lds[NCF][33];
    const int z  = blockIdx.z;
    const int xb = blockIdx.x * 32;
    const int y  = blockIdx.y;
    if (z < NV) {
        transpose_tile<NCF>(feat + (size_t)(z*NCF)*HWN + y*WW + xb,
                            featT + (size_t)(z*HWN + y*WW + xb) * NCF,
                            lds, threadIdx.x);
    } else {
        transpose_tile<NCD>(deps + (size_t)((z - NV)*NCD)*HWN + y*WW + xb,
                            depsT + (size_t)((z - NV)*HWN + y*WW + xb) * NCD,
                            lds, threadIdx.x);
    }
}

// ---------------------------------------------------------------------------
// Main: block = 256 threads = 4 waves = 8 pixels x 32 depths.
// Wave w handles depths 8w..8w+7.
// Feat phase: lane = (pl<3b high>, cg<3b low>); lane cg computes the bilinear
// setup for depth jj==cg (both views); main loop broadcasts it via __shfl.
// grid = HWN/8 = 2560 blocks.
// ---------------------------------------------------------------------------
__global__ __launch_bounds__(256) void cost_volume_k(
    const float* __restrict__ featT,   // (V,HW,32)
    const float* __restrict__ depsT,   // (V,HW,8)
    const float* __restrict__ dvals,   // (D,HW)
    const float* __restrict__ regw,    // 40
    const float* __restrict__ pws,     // 24 (uniform -> scalar loads)
    float* __restrict__ out)
{
    __shared__ float cl [ND][9];
    __shared__ float dvl[ND][9];
    __shared__ float smax[8], sisum[8];

    const int t    = threadIdx.x;
    const int lane = t & 63;
    const int wid  = t >> 6;
    const int cg   = lane & 7;
    const int pl   = lane >> 3;
    const int pixg = blockIdx.x * 8 + pl;
    const int y    = pixg / WW;
    const int x    = pixg - y * WW;
    const float fx = (float)x, fy = (float)y;
    const int dbase = wid * 8;

    // per-view ray (depth-independent); pws is uniform -> s_loads
    float RX[2], RY[2], RZ[2], T0[2], T1[2], T2[2];
    #pragma unroll
    for (int v = 0; v < 2; v++) {
        const float* q = pws + v*12;
        RX[v] = q[0]*fx + q[1]*fy + q[2];
        RY[v] = q[3]*fx + q[4]*fy + q[5];
        RZ[v] = q[6]*fx + q[7]*fy + q[8];
        T0[v] = q[9]; T1[v] = q[10]; T2[v] = q[11];
    }

    // helper: full bilinear setup for one (depth-value, view, stride CH)
    auto bsetup = [&](float dvv, int v, int CH, float& w00, float& w10,
                      float& w01, float& w11, int& o00, int& o10,
                      int& o01, int& o11) {
        float pz = RZ[v]*dvv + T2[v];
        float iz = __builtin_amdgcn_rcpf(pz);
        float px = (RX[v]*dvv + T0[v]) * iz;
        float py = (RY[v]*dvv + T1[v]) * iz;
        float x0f = floorf(px), y0f = floorf(py);
        int x0 = (int)x0f, y0 = (int)y0f;
        float wx = px - x0f, wy = py - y0f;
        float omx = 1.f - wx, omy = 1.f - wy;
        bool vx0 = (x0 >= 0) & (x0 < WW);
        bool vx1 = (x0+1 >= 0) & (x0+1 < WW);
        bool vy0 = (y0 >= 0) & (y0 < HH);
        bool vy1 = (y0+1 >= 0) & (y0+1 < HH);
        w00 = (vx0 && vy0) ? omx*omy : 0.f;
        w10 = (vx1 && vy0) ? wx*omy  : 0.f;
        w01 = (vx0 && vy1) ? omx*wy  : 0.f;
        w11 = (vx1 && vy1) ? wx*wy   : 0.f;
        int xc0 = min(max(x0,   0), WW-1);
        int xc1 = min(max(x0+1, 0), WW-1);
        int yc0 = min(max(y0,   0), HH-1);
        int yc1 = min(max(y0+1, 0), HH-1);
        o00 = (yc0*WW + xc0)*CH;
        o10 = (yc0*WW + xc1)*CH;
        o01 = (yc1*WW + xc0)*CH;
        o11 = (yc1*WW + xc1)*CH;
    };

    // ================== FEAT PHASE ==================
    {
        // lane cg owns the setup for depth jj = cg (both views)
        float dvv_own = dvals[(dbase + cg)*HWN + pixg];
        dvl[dbase + cg][pl] = dvv_own;
        float SW00[2], SW10[2], SW01[2], SW11[2];
        int   SO00[2], SO10[2], SO01[2], SO11[2];
        #pragma unroll
        for (int v = 0; v < 2; v++)
            bsetup(dvv_own, v, NCF, SW00[v], SW10[v], SW01[v], SW11[v],
                   SO00[v], SO10[v], SO01[v], SO11[v]);

        float4 r4 = *(const float4*)(featT + (size_t)pixg*NCF + cg*4);
        float4 w4 = *(const float4*)(regw + cg*4);
        const float wca0 = w4.x*(1.f/3.f), wca1 = w4.y*(1.f/3.f),
                    wca2 = w4.z*(1.f/3.f), wca3 = w4.w*(1.f/3.f);
        const float wcb0 = w4.x*(1.f/9.f), wcb1 = w4.y*(1.f/9.f),
                    wcb2 = w4.z*(1.f/9.f), wcb3 = w4.w*(1.f/9.f);
        const float rx0 = r4.x, rx1 = r4.y, rx2 = r4.z, rx3 = r4.w;
        const float* b1 = featT + (size_t)1*HWN*NCF + cg*4;
        const float* b2 = featT + (size_t)2*HWN*NCF + cg*4;
        const int plbase = lane & 0x38;

        #pragma unroll 2
        for (int jj = 0; jj < 8; jj++) {
            const int src = plbase | jj;
            float s0 = rx0, s1 = rx1, s2 = rx2, s3 = rx3;
            float q0 = rx0*rx0, q1 = rx1*rx1, q2 = rx2*rx2, q3 = rx3*rx3;

            #pragma unroll
            for (int v = 0; v < 2; v++) {
                float W00 = __shfl(SW00[v], src, 64);
                float W10 = __shfl(SW10[v], src, 64);
                float W01 = __shfl(SW01[v], src, 64);
                float W11 = __shfl(SW11[v], src, 64);
                int   o00 = __shfl(SO00[v], src, 64);
                int   o10 = __shfl(SO10[v], src, 64);
                int   o01 = __shfl(SO01[v], src, 64);
                int   o11 = __shfl(SO11[v], src, 64);
                const float* b = v ? b2 : b1;
                float4 f00 = *(const float4*)(b + o00);
                float4 f10 = *(const float4*)(b + o10);
                float4 f01 = *(const float4*)(b + o01);
                float4 f11 = *(const float4*)(b + o11);
                float wv0 = W00*f00.x + W10*f10.x + W01*f01.x + W11*f11.x;
                float wv1 = W00*f00.y + W10*f10.y + W01*f01.y + W11*f11.y;
                float wv2 = W00*f00.z + W10*f10.z + W01*f01.z + W11*f11.z;
                float wv3 = W00*f00.w + W10*f10.w + W01*f01.w + W11*f11.w;
                s0 += wv0; q0 = fmaf(wv0, wv0, q0);
                s1 += wv1; q1 = fmaf(wv1, wv1, q1);
                s2 += wv2; q2 = fmaf(wv2, wv2, q2);
                s3 += wv3; q3 = fmaf(wv3, wv3, q3);
            }
            float part = wca0*q0 - wcb0*s0*s0;
            part = fmaf(wca1, q1, part); part = fmaf(-wcb1, s1*s1, part);
            part = fmaf(wca2, q2, part); part = fmaf(-wcb2, s2*s2, part);
            part = fmaf(wca3, q3, part); part = fmaf(-wcb3, s3*s3, part);
            part += __shfl_xor(part, 1);
            part += __shfl_xor(part, 2);
            part += __shfl_xor(part, 4);
            if (cg == jj) cl[dbase + jj][pl] = part;
        }
    }
    __syncthreads();

    // ================== DEPS PHASE ==================
    {
        const int cgd  = lane & 1;       // float4 group in 8 channels
        const int dsub = (lane >> 1) & 3;
        float4 r4 = *(const float4*)(depsT + (size_t)pixg*NCD + cgd*4);
        float4 w4 = *(const float4*)(regw + NCF + cgd*4);
        const float wca0 = w4.x*(1.f/3.f), wca1 = w4.y*(1.f/3.f),
                    wca2 = w4.z*(1.f/3.f), wca3 = w4.w*(1.f/3.f);
        const float wcb0 = w4.x*(1.f/9.f), wcb1 = w4.y*(1.f/9.f),
                    wcb2 = w4.z*(1.f/9.f), wcb3 = w4.w*(1.f/9.f);
        const float rx0 = r4.x, rx1 = r4.y, rx2 = r4.z, rx3 = r4.w;
        const float* b1 = depsT + (size_t)1*HWN*NCD + cgd*4;
        const float* b2 = depsT + (size_t)2*HWN*NCD + cgd*4;

        #pragma unroll
        for (int i = 0; i < 2; i++) {
            const int d = dbase + dsub + 4*i;
            float dvv = dvl[d][pl];
            float s0 = rx0, s1 = rx1, s2 = rx2, s3 = rx3;
            float q0 = rx0*rx0, q1 = rx1*rx1, q2 = rx2*rx2, q3 = rx3*rx3;

            #pragma unroll
            for (int v = 0; v < 2; v++) {
                float W00, W10, W01, W11; int o00, o10, o01, o11;
                bsetup(dvv, v, NCD, W00, W10, W01, W11, o00, o10, o01, o11);
                const float* b = v ? b2 : b1;
                float4 f00 = *(const float4*)(b + o00);
                float4 f10 = *(const float4*)(b + o10);
                float4 f01 = *(const float4*)(b + o01);
                float4 f11 = *(const float4*)(b + o11);
                float wv0 = W00*f00.x + W10*f10.x + W01*f01.x + W11*f11.x;
                float wv1 = W00*f00.y + W10*f10.y + W01*f01.y + W11*f11.y;
                float wv2 = W00*f00.z + W10*f10.z + W01*f01.z + W11*f11.z;
                float wv3 = W00*f00.w + W10*f10.w + W01*f01.w + W11*f11.w;
                s0 += wv0; q0 = fmaf(wv0, wv0, q0);
                s1 += wv1; q1 = fmaf(wv1, wv1, q1);
                s2 += wv2; q2 = fmaf(wv2, wv2, q2);
                s3 += wv3; q3 = fmaf(wv3, wv3, q3);
            }
            float part = wca0*q0 - wcb0*s0*s0;
            part = fmaf(wca1, q1, part); part = fmaf(-wcb1, s1*s1, part);
            part = fmaf(wca2, q2, part); part = fmaf(-wcb2, s2*s2, part);
            part = fmaf(wca3, q3, part); part = fmaf(-wcb3, s3*s3, part);
            part += __shfl_xor(part, 1);
            if (cgd == 0) cl[d][pl] += part;   // disjoint d-ranges per wave
        }
    }
    __syncthreads();

    // ================== SOFTMAX + MOMENTS ==================
    if (t < 8) {
        const int plx  = t;
        const int pixo = blockIdx.x * 8 + plx;
        float m = -1e30f;
        #pragma unroll
        for (int d = 0; d < ND; d++) m = fmaxf(m, cl[d][plx]);
        float sum = 0.f, pd = 0.f, pd2 = 0.f;
        #pragma unroll
        for (int d = 0; d < ND; d++) {
            float e   = __expf(cl[d][plx] - m);
            float dvv = dvl[d][plx];
            sum += e;
            pd  = fmaf(e, dvv, pd);
            pd2 = fmaf(e, dvv*dvv, pd2);
        }
        float isum  = 1.f / sum;
        float depth = pd * isum;
        float sv    = pd2 * isum - depth*depth;
        float ev    = LAMBF * sqrtf(fmaxf(sv, 0.f));
        smax[plx]  = m;
        sisum[plx] = isum;
        out[pixo]       = depth;
        out[HWN + pixo] = ev;
    }
    __syncthreads();
    {
        const int plx  = t & 7;
        const int dd   = t >> 3;
        const int pixo = blockIdx.x * 8 + plx;
        out[2*HWN + dd*HWN + pixo] = __expf(cl[dd][plx] - smax[plx]) * sisum[plx];
    }
}

// ---------------------------------------------------------------------------
extern "C" void kernel_launch(void* const* d_in, const int* in_sizes, int n_in,
                              void* d_out, int out_size, void* d_ws, size_t ws_size,
                              hipStream_t stream) {
    const float* features = (const float*)d_in[0];   // (V,1,32,H,W)
    const float* deps     = (const float*)d_in[1];   // (V,1,8,H,W)
    const float* proj     = (const float*)d_in[2];   // (1,V,4,4)
    const float* dvals    = (const float*)d_in[3];   // (1,D,H,W)
    const float* regw     = (const float*)d_in[4];   // (1,40)

    float* ws    = (float*)d_ws;
    float* projw = ws;                         // 24 floats (64 reserved)
    float* featT = ws + 64;                    // 3*HW*32
    float* depsT = featT + (size_t)NV*HWN*NCF; // 3*HW*8

    dim3 tg(WW/32, HH, 2*NV);
    prep_k<<<tg, 256, 0, stream>>>(features, deps, proj, featT, depsT, projw);

    cost_volume_k<<<HWN/8, 256, 0, stream>>>(featT, depsT, dvals, regw, projw,
                                             (float*)d_out);
}